// Round 5
// baseline (207.741 us; speedup 1.0000x reference)
//
#include <hip/hip_runtime.h>
#include <hip/hip_bf16.h>

// Problem constants (from reference setup_inputs)
#define BB 2
#define NH 4
#define NN 2304
#define DIM 64
#define DH 8
#define HID 32
#define KN 314   // neighbors per point

// Workspace layout:
#define QKV_OFF 0
#define QKV_SZ  (BB*NN*96)            // floats
#define A_OFF   (QKV_OFF + QKV_SZ)
#define A_SZ    (BB*NH*NN*HID)
#define BK_OFF  (A_OFF + A_SZ)
#define BK_SZ   (BB*NH*NN*HID)
#define V_OFF   (BK_OFF + BK_SZ)
#define V_SZ    (BB*NH*NN*DH)
#define DEN_OFF (V_OFF + V_SZ)
#define DEN_SZ  (BB*NH*KN*DH)
#define AGG_OFF (DEN_OFF + DEN_SZ)
#define AGG_SZ  (BB*NH*NN*DH)
#define NUM_OFF (AGG_OFF + AGG_SZ)    // float offset where bf16 num buffer starts
#define NUM_ELTS ((size_t)BB*NH*NN*KN*DH)          // 46.3M bf16 elements = 92.6 MB
#define WS_NEED_BYTES ((size_t)NUM_OFF*4 + NUM_ELTS*2)

typedef float v2f __attribute__((ext_vector_type(2)));
#define SWZ(x, imm) __int_as_float(__builtin_amdgcn_ds_swizzle(__float_as_int(x), imm))

// ---------------- K1: qkv = x @ w_qkv ----------------
__global__ void qkv_kernel(const float* __restrict__ x, const float* __restrict__ w_qkv, float* ws){
    int t = blockIdx.x*256 + threadIdx.x;
    if (t >= BB*NN*96) return;
    int c = t % 96;
    int p = (t / 96) % NN;
    int b = t / (96*NN);
    const float* xr = x + (b*NN + p)*DIM;
    float acc = 0.f;
    #pragma unroll 8
    for (int dd=0; dd<DIM; dd++)
        acc = fmaf(xr[dd], w_qkv[dd*96 + c], acc);
    ws[QKV_OFF + (b*NN + p)*96 + c] = acc;
}

// ---------------- K2: A = w1.q + b1 ; Bk = w1.k ; V copy ----------------
__global__ void ab_kernel(const float* __restrict__ w1, const float* __restrict__ b1, float* ws){
    int t = blockIdx.x*256 + threadIdx.x;
    if (t >= BB*NH*NN*HID) return;
    int e  = t % HID;
    int p  = (t / HID) % NN;
    int hh = (t / (HID*NN)) % NH;
    int b  = t / (HID*NN*NH);
    const float* qkv = ws + QKV_OFF + (b*NN + p)*96;
    const float* w1r = w1 + (hh*HID + e)*DH;
    float sa = b1[hh*HID + e];
    float sb = 0.f;
    #pragma unroll
    for (int d=0; d<DH; d++){
        float wv = w1r[d];
        sa = fmaf(wv, qkv[hh*DH + d],      sa);
        sb = fmaf(wv, qkv[32 + hh*DH + d], sb);
    }
    int base = ((b*NH + hh)*NN + p);
    ws[A_OFF  + base*HID + e] = sa;
    ws[BK_OFF + base*HID + e] = sb;
    if (e < DH)
        ws[V_OFF + base*DH + e] = qkv[64 + hh*DH + e];
}

// w2 slice for lane dd, slot m holds d = dd ^ bitrev3(m) -> select-free butterfly
__device__ __forceinline__ void load_w2p(const float* __restrict__ w2, int hh, int dd,
                                         v2f w2a[8], v2f w2b[8]){
    #pragma unroll
    for (int m=0; m<8; m++){
        int d = dd ^ (((m&1)<<2) | (m&2) | ((m>>2)&1));   // dd ^ bitrev3(m)
        const float* wp = w2 + (hh*DH + d)*HID + 4*dd;
        v2f a; a.x = wp[0]; a.y = wp[1];
        v2f b; b.x = wp[2]; b.y = wp[3];
        w2a[m] = a; w2b[m] = b;
    }
}

// pr[8] (slot m at lane dd holds d = dd^bitrev3(m)) -> full sim for d=dd on lane dd
__device__ __forceinline__ float butterfly8p(float pr[8]){
    float q0 = pr[0] + SWZ(pr[4], 0x041F);   // xor 1
    float q1 = pr[1] + SWZ(pr[5], 0x041F);
    float q2 = pr[2] + SWZ(pr[6], 0x041F);
    float q3 = pr[3] + SWZ(pr[7], 0x041F);
    float r0 = q0 + SWZ(q2, 0x081F);         // xor 2
    float r1 = q1 + SWZ(q3, 0x081F);
    return r0 + SWZ(r1, 0x101F);             // xor 4
}

// one i-iteration of pass1: returns exp(sim), optionally stores bf16 num
template<bool BIG>
__device__ __forceinline__ float p1_body(int i, const int* __restrict__ idxc,
        const float* __restrict__ Abuf, const float* __restrict__ Bbuf,
        const v2f* __restrict__ w2a, const v2f* __restrict__ w2b, float b2v,
        bool jv, __hip_bfloat16* __restrict__ nump)
{
    int p = idxc[(size_t)i*KN];
    float4 avv = *(const float4*)(Abuf + (size_t)i*HID);
    float4 bvv = *(const float4*)(Bbuf + (size_t)p*HID);
    v2f a0; a0.x=avv.x; a0.y=avv.y;
    v2f a1; a1.x=avv.z; a1.y=avv.w;
    v2f c0; c0.x=bvv.x; c0.y=bvv.y;
    v2f c1; c1.x=bvv.z; c1.y=bvv.w;
    v2f z;  z.x=0.f; z.y=0.f;
    v2f r0 = __builtin_elementwise_max(a0-c0, z);
    v2f r1 = __builtin_elementwise_max(a1-c1, z);
    float pr[8];
    #pragma unroll
    for (int m=0; m<8; m++){
        v2f t = w2a[m]*r0;
        t = __builtin_elementwise_fma(w2b[m], r1, t);
        pr[m] = t.x + t.y;
    }
    float sim = butterfly8p(pr) + b2v;
    float nm = __expf(sim);
    if (BIG && jv) nump[(size_t)i*KN*DH] = __float2bfloat16(nm);
    return nm;
}

// ---------------- K3: pass 1 — den[j,d] = sum_i exp(sim); optionally store num ----------------
// grid: (640, NH, BB); blockIdx.x = sg*16 + ic ; block = 256 (4 waves), 36 i's per wave
template<bool BIG>
__global__ __launch_bounds__(256, 8) void pass1_kernel(const int* __restrict__ idx,
                                                       const float* __restrict__ w2,
                                                       const float* __restrict__ b2, float* ws){
    int sgic = blockIdx.x, hh = blockIdx.y, b = blockIdx.z;
    int sg = sgic >> 4, ic = sgic & 15;
    int w = threadIdx.x >> 6, lane = threadIdx.x & 63;
    int g = lane >> 3, dd = lane & 7;
    int j = sg*8 + g;
    bool jv = (j < KN);
    int jj = jv ? j : (KN-1);
    int bh = b*NH + hh;

    v2f w2a[8], w2b[8];
    load_w2p(w2, hh, dd, w2a, w2b);
    float b2v = b2[hh*DH + dd];

    const float* Abuf = ws + A_OFF  + (size_t)bh*NN*HID + 4*dd;
    const float* Bbuf = ws + BK_OFF + (size_t)bh*NN*HID + 4*dd;
    __hip_bfloat16* nump = (__hip_bfloat16*)(ws + NUM_OFF)
                           + (size_t)bh*NN*KN*DH + (size_t)jj*DH + dd;
    const int* idxc = idx + jj;

    float d0 = 0.f, d1 = 0.f;
    int i0 = ic*144 + w*36;
    for (int ii=0; ii<36; ii+=2){
        d0 += p1_body<BIG>(i0+ii,   idxc, Abuf, Bbuf, w2a, w2b, b2v, jv, nump);
        d1 += p1_body<BIG>(i0+ii+1, idxc, Abuf, Bbuf, w2a, w2b, b2v, jv, nump);
    }
    float den_acc = d0 + d1;
    if (!jv) den_acc = 0.f;

    __shared__ float red[256];
    red[threadIdx.x] = den_acc;
    __syncthreads();
    if (w == 0 && jv){
        float s = red[lane] + red[lane+64] + red[lane+128] + red[lane+192];
        atomicAdd(ws + DEN_OFF + ((size_t)bh*KN + j)*DH + dd, s);
    }
}

// ---------------- K3.5: invert den in place ----------------
__global__ void invden_kernel(float* ws){
    int t = blockIdx.x*256 + threadIdx.x;
    if (t < DEN_SZ){
        float* d = ws + DEN_OFF;
        d[t] = 1.0f / d[t];
    }
}

// ---------------- K4-fast: agg[i,d] = sum_j num[i,j,d]*invd[j,d]*v[p,d] ----------------
// grid: (288, NH, BB); block 256 = 4 waves, 2 i per wave
__global__ __launch_bounds__(256) void pass2f_kernel(const int* __restrict__ idx, float* ws){
    int hh = blockIdx.y, b = blockIdx.z;
    int w = threadIdx.x >> 6, lane = threadIdx.x & 63;
    int g = lane >> 3, dd = lane & 7;
    int bh = b*NH + hh;

    __shared__ float invs[KN*DH];
    {
        const float* invd = ws + DEN_OFF + (size_t)bh*KN*DH;
        for (int t = threadIdx.x; t < KN*DH; t += 256) invs[t] = invd[t];
    }
    __syncthreads();

    const float* Vbuf = ws + V_OFF + (size_t)bh*NN*DH;
    float* agg = ws + AGG_OFF + (size_t)bh*NN*DH;

    #pragma unroll
    for (int ii=0; ii<2; ii++){
        int i = blockIdx.x*8 + w*2 + ii;
        const __hip_bfloat16* nump = (const __hip_bfloat16*)(ws + NUM_OFF)
                                     + ((size_t)bh*NN + i)*KN*DH;
        const int* idxr = idx + (size_t)i*KN;

        float acc = 0.f;
        #pragma unroll 2
        for (int sg=0; sg<40; sg++){
            int j = sg*8 + g;
            bool jvv = (j < KN);
            int jj = jvv ? j : (KN-1);
            int p = idxr[jj];
            float nm = __bfloat162float(nump[(size_t)jj*DH + dd]);
            float att = jvv ? nm * invs[jj*DH + dd] : 0.f;
            acc = fmaf(att, Vbuf[(size_t)p*DH + dd], acc);
        }
        acc += __shfl_xor(acc, 8, 64);
        acc += __shfl_xor(acc, 16, 64);
        acc += __shfl_xor(acc, 32, 64);
        if (g == 0) agg[(size_t)i*DH + dd] = acc;
    }
}

// ---------------- K4-fallback: recompute sim (round-3 verbatim) ----------------
__device__ __forceinline__ void load_w2s(const float* __restrict__ w2, int hh, int dd, float w2s[8][4]){
    #pragma unroll
    for (int m=0; m<8; m++){
        int d = ((m&1)<<2) | (m&2) | ((m>>2)&1);
        const float* wp = w2 + (hh*DH + d)*HID + 4*dd;
        w2s[m][0]=wp[0]; w2s[m][1]=wp[1]; w2s[m][2]=wp[2]; w2s[m][3]=wp[3];
    }
}
__device__ __forceinline__ float butterfly8(float pr[8], int dd){
    int b0 = dd&1, b1 = (dd>>1)&1, b2b = (dd>>2)&1;
    float q[4];
    #pragma unroll
    for (int t=0; t<4; t++){
        float send = pr[4*(1-b0)+t];
        float recv = __shfl_xor(send, 1, 64);
        q[t] = pr[4*b0+t] + recv;
    }
    float r[2];
    #pragma unroll
    for (int t=0; t<2; t++){
        float send = q[2*(1-b1)+t];
        float recv = __shfl_xor(send, 2, 64);
        r[t] = q[2*b1+t] + recv;
    }
    float send = r[1-b2b];
    float recv = __shfl_xor(send, 4, 64);
    return r[b2b] + recv;
}
__global__ __launch_bounds__(256) void pass2_kernel(const int* __restrict__ idx,
                                                    const float* __restrict__ w2,
                                                    const float* __restrict__ b2, float* ws){
    int ic = blockIdx.x, hh = blockIdx.y, b = blockIdx.z;
    int w = threadIdx.x >> 6, lane = threadIdx.x & 63;
    int g = lane >> 3, dd = lane & 7;

    float w2s[8][4];
    load_w2s(w2, hh, dd, w2s);
    float b2v = b2[hh*DH + dd];

    const float* Abuf = ws + A_OFF  + (size_t)(b*NH + hh)*NN*HID;
    const float* Bbuf = ws + BK_OFF + (size_t)(b*NH + hh)*NN*HID;
    const float* Vbuf = ws + V_OFF  + (size_t)(b*NH + hh)*NN*DH;
    const float* invd = ws + DEN_OFF + (size_t)(b*NH + hh)*KN*DH;
    float*       agg  = ws + AGG_OFF + (size_t)(b*NH + hh)*NN*DH;

    int i0 = ic*8 + w*2;
    #pragma unroll
    for (int ii=0; ii<2; ii++){
        int i = i0 + ii;
        float4 av = *(const float4*)(Abuf + (size_t)i*HID + 4*dd);
        float acc = 0.f;
        for (int sg=0; sg<40; sg++){
            int j = sg*8 + g;
            bool jvv = (j < KN);
            int jj = jvv ? j : (KN-1);
            int p = idx[i*KN + jj];
            float4 bv = *(const float4*)(Bbuf + (size_t)p*HID + 4*dd);
            float r0 = fmaxf(av.x-bv.x, 0.f), r1 = fmaxf(av.y-bv.y, 0.f);
            float r2 = fmaxf(av.z-bv.z, 0.f), r3 = fmaxf(av.w-bv.w, 0.f);
            float pr[8];
            #pragma unroll
            for (int m=0; m<8; m++)
                pr[m] = fmaf(w2s[m][0],r0, fmaf(w2s[m][1],r1, fmaf(w2s[m][2],r2, w2s[m][3]*r3)));
            float sim = butterfly8(pr, dd) + b2v;
            float attn = jvv ? (__expf(sim) * invd[(size_t)jj*DH + dd]) : 0.f;
            acc = fmaf(attn, Vbuf[(size_t)p*DH + dd], acc);
        }
        acc += __shfl_xor(acc, 8, 64);
        acc += __shfl_xor(acc, 16, 64);
        acc += __shfl_xor(acc, 32, 64);
        if (g == 0) agg[(size_t)i*DH + dd] = acc;
    }
}

// ---------------- K5: out = agg @ w_out + b_out ----------------
__global__ void out_kernel(const float* __restrict__ w_out, const float* __restrict__ b_out,
                           const float* __restrict__ ws, float* __restrict__ out){
    int t = blockIdx.x*256 + threadIdx.x;
    if (t >= BB*NN*DIM) return;
    int c = t % DIM;
    int p = (t / DIM) % NN;
    int b = t / (DIM*NN);
    const float* agg = ws + AGG_OFF;
    float s = b_out[c];
    #pragma unroll
    for (int f=0; f<32; f++){
        int hh = f >> 3, d = f & 7;
        s = fmaf(agg[(((size_t)(b*NH + hh)*NN) + p)*DH + d], w_out[f*DIM + c], s);
    }
    out[t] = s;
}

extern "C" void kernel_launch(void* const* d_in, const int* in_sizes, int n_in,
                              void* d_out, int out_size, void* d_ws, size_t ws_size,
                              hipStream_t stream){
    const float* x     = (const float*)d_in[0];
    const int*   idx   = (const int*)d_in[1];
    const float* w_qkv = (const float*)d_in[2];
    const float* w1    = (const float*)d_in[3];
    const float* b1    = (const float*)d_in[4];
    const float* w2    = (const float*)d_in[5];
    const float* b2    = (const float*)d_in[6];
    const float* w_out = (const float*)d_in[7];
    const float* b_out = (const float*)d_in[8];
    float* ws  = (float*)d_ws;
    float* out = (float*)d_out;

    bool big = (ws_size >= WS_NEED_BYTES);

    hipMemsetAsync(ws + DEN_OFF, 0, DEN_SZ*sizeof(float), stream);

    qkv_kernel<<<(BB*NN*96 + 255)/256, 256, 0, stream>>>(x, w_qkv, ws);
    ab_kernel <<<(BB*NH*NN*HID + 255)/256, 256, 0, stream>>>(w1, b1, ws);
    if (big){
        pass1_kernel<true ><<<dim3(640, NH, BB), 256, 0, stream>>>(idx, w2, b2, ws);
        invden_kernel<<<(DEN_SZ + 255)/256, 256, 0, stream>>>(ws);
        pass2f_kernel<<<dim3(288, NH, BB), 256, 0, stream>>>(idx, ws);
    } else {
        pass1_kernel<false><<<dim3(640, NH, BB), 256, 0, stream>>>(idx, w2, b2, ws);
        invden_kernel<<<(DEN_SZ + 255)/256, 256, 0, stream>>>(ws);
        pass2_kernel<<<dim3(288, NH, BB), 256, 0, stream>>>(idx, w2, b2, ws);
    }
    out_kernel<<<(BB*NN*DIM + 255)/256, 256, 0, stream>>>(w_out, b_out, ws, out);
}

// Round 6
// 190.990 us; speedup vs baseline: 1.0877x; 1.0877x over previous
//
#include <hip/hip_runtime.h>
#include <hip/hip_bf16.h>

// Problem constants (from reference setup_inputs)
#define BB 2
#define NH 4
#define NN 2304
#define DIM 64
#define DH 8
#define HID 32
#define KN 314   // neighbors per point

// Workspace layout:
#define QKV_OFF 0
#define QKV_SZ  (BB*NN*96)            // floats
#define A_OFF   (QKV_OFF + QKV_SZ)
#define A_SZ    (BB*NH*NN*HID)
#define BK_OFF  (A_OFF + A_SZ)
#define BK_SZ   (BB*NH*NN*HID)
#define V_OFF   (BK_OFF + BK_SZ)
#define V_SZ    (BB*NH*NN*DH)
#define DEN_OFF (V_OFF + V_SZ)
#define DEN_SZ  (BB*NH*KN*DH)
#define AGG_OFF (DEN_OFF + DEN_SZ)
#define AGG_SZ  (BB*NH*NN*DH)
#define NUM_OFF (AGG_OFF + AGG_SZ)    // float offset where bf16 num buffer starts
#define NUM_ELTS ((size_t)BB*NH*NN*KN*DH)          // 46.3M bf16 elements = 92.6 MB
#define WS_NEED_BYTES ((size_t)NUM_OFF*4 + NUM_ELTS*2)

typedef float v2f __attribute__((ext_vector_type(2)));
typedef __attribute__((ext_vector_type(8))) short bf16x8;
typedef __attribute__((ext_vector_type(4))) float f32x4;
#define SWZ(x, imm) __int_as_float(__builtin_amdgcn_ds_swizzle(__float_as_int(x), imm))

static __device__ __forceinline__ short f2bf(float f){
    __hip_bfloat16 h = __float2bfloat16(f);
    short s; __builtin_memcpy(&s, &h, 2); return s;
}
static __device__ __forceinline__ float bfbits2f(unsigned short u){
    return __uint_as_float(((unsigned)u) << 16);
}

// ---------------- K1: qkv = x @ w_qkv ----------------
__global__ void qkv_kernel(const float* __restrict__ x, const float* __restrict__ w_qkv, float* ws){
    int t = blockIdx.x*256 + threadIdx.x;
    if (t >= BB*NN*96) return;
    int c = t % 96;
    int p = (t / 96) % NN;
    int b = t / (96*NN);
    const float* xr = x + (b*NN + p)*DIM;
    float acc = 0.f;
    #pragma unroll 8
    for (int dd=0; dd<DIM; dd++)
        acc = fmaf(xr[dd], w_qkv[dd*96 + c], acc);
    ws[QKV_OFF + (b*NN + p)*96 + c] = acc;
}

// ---------------- K2: A = w1.q + b1 ; Bk = w1.k ; V copy ----------------
__global__ void ab_kernel(const float* __restrict__ w1, const float* __restrict__ b1, float* ws){
    int t = blockIdx.x*256 + threadIdx.x;
    if (t >= BB*NH*NN*HID) return;
    int e  = t % HID;
    int p  = (t / HID) % NN;
    int hh = (t / (HID*NN)) % NH;
    int b  = t / (HID*NN*NH);
    const float* qkv = ws + QKV_OFF + (b*NN + p)*96;
    const float* w1r = w1 + (hh*HID + e)*DH;
    float sa = b1[hh*HID + e];
    float sb = 0.f;
    #pragma unroll
    for (int d=0; d<DH; d++){
        float wv = w1r[d];
        sa = fmaf(wv, qkv[hh*DH + d],      sa);
        sb = fmaf(wv, qkv[32 + hh*DH + d], sb);
    }
    int base = ((b*NH + hh)*NN + p);
    ws[A_OFF  + base*HID + e] = sa;
    ws[BK_OFF + base*HID + e] = sb;
    if (e < DH)
        ws[V_OFF + base*DH + e] = qkv[64 + hh*DH + e];
}

// ---------------- K3 (big path): MFMA pass1 ----------------
// sim[j,d] = relu(A[i]-B[p_j]) . w2^T + b2 as 16x16x32 MFMA (M=j, N=d pad 16, K=e)
// grid (20, 8, 8): x=j-tile, y=strip-block (4 waves each -> 32 strips of 72 i), z=bh
__global__ __launch_bounds__(256, 4) void pass1_mfma(const int* __restrict__ idx,
                                                     const float* __restrict__ w2,
                                                     const float* __restrict__ b2, float* ws){
    int jt = blockIdx.x;
    int bh = blockIdx.z;
    int hh = bh & (NH-1);
    int w = threadIdx.x >> 6, lane = threadIdx.x & 63;
    int n  = lane & 15;    // MFMA col = d (valid < 8)
    int kg = lane >> 4;    // e-slice group: e = kg*8 .. kg*8+7
    int strip = blockIdx.y*4 + w;   // 0..31
    int i0 = strip*72;

    // B-frag: w2^T column n, k-slice kg*8+t  (4 VGPRs, zero-padded cols 8..15)
    bf16x8 bfrag;
    #pragma unroll
    for (int t=0; t<8; t++){
        float wv = (n < DH) ? w2[(hh*DH + n)*HID + kg*8 + t] : 0.f;
        bfrag[t] = f2bf(wv);
    }
    float b2v = (n < DH) ? b2[hh*DH + n] : 0.f;
    f32x4 cinit; cinit[0]=b2v; cinit[1]=b2v; cinit[2]=b2v; cinit[3]=b2v;

    int jrow = jt*16 + n;                 // A-operand row this lane feeds
    int jj = jrow < KN ? jrow : (KN-1);
    int jr0 = jt*16 + kg*4;               // C rows this lane owns: jr0..jr0+3

    const float* Abuf = ws + A_OFF  + (size_t)bh*NN*HID;
    const float* Bbuf = ws + BK_OFF + (size_t)bh*NN*HID;
    const int* idxp = idx + (size_t)i0*KN + jj;
    const float* ap = Abuf + (size_t)i0*HID + kg*8;
    unsigned short* np = (unsigned short*)(ws + NUM_OFF)
        + ((size_t)bh*NN + i0)*KN*DH + (size_t)jr0*DH + n;

    f32x4 den; den[0]=0.f; den[1]=0.f; den[2]=0.f; den[3]=0.f;
    bool nok = (n < DH);

    int pcur = *idxp; idxp += KN;
    for (int ii=0; ii<72; ii++){
        float4 a0 = *(const float4*)ap;
        float4 a1 = *(const float4*)(ap+4);
        const float* bp = Bbuf + (size_t)pcur*HID + kg*8;
        float4 c0 = *(const float4*)bp;
        float4 c1 = *(const float4*)(bp+4);
        if (ii < 71){ pcur = *idxp; idxp += KN; }
        ap += HID;

        bf16x8 afrag;
        afrag[0] = f2bf(fmaxf(a0.x - c0.x, 0.f));
        afrag[1] = f2bf(fmaxf(a0.y - c0.y, 0.f));
        afrag[2] = f2bf(fmaxf(a0.z - c0.z, 0.f));
        afrag[3] = f2bf(fmaxf(a0.w - c0.w, 0.f));
        afrag[4] = f2bf(fmaxf(a1.x - c1.x, 0.f));
        afrag[5] = f2bf(fmaxf(a1.y - c1.y, 0.f));
        afrag[6] = f2bf(fmaxf(a1.z - c1.z, 0.f));
        afrag[7] = f2bf(fmaxf(a1.w - c1.w, 0.f));

        f32x4 dres = __builtin_amdgcn_mfma_f32_16x16x32_bf16(afrag, bfrag, cinit, 0, 0, 0);

        #pragma unroll
        for (int r=0; r<4; r++){
            float e = __expf(dres[r]);
            den[r] += e;
            if (nok && (jr0 + r) < KN)
                np[r*DH] = (unsigned short)f2bf(e);
        }
        np += (size_t)KN*DH;
    }

    if (nok){
        #pragma unroll
        for (int r=0; r<4; r++){
            if (jr0 + r < KN)
                atomicAdd(ws + DEN_OFF + ((size_t)bh*KN + jr0 + r)*DH + n, den[r]);
        }
    }
}

// ---------------- K3.5: invert den in place ----------------
__global__ void invden_kernel(float* ws){
    int t = blockIdx.x*256 + threadIdx.x;
    if (t < DEN_SZ){
        float* d = ws + DEN_OFF;
        d[t] = 1.0f / d[t];
    }
}

// ---------------- K4-fast: agg[i,d] = sum_j num[i,j,d]*invd[j,d]*v[p,d] ----------------
// grid: (288, NH, BB); block 256 = 4 waves, 2 i per wave (interleaved, sw-pipelined)
__global__ __launch_bounds__(256) void pass2f_kernel(const int* __restrict__ idx, float* ws){
    int hh = blockIdx.y, b = blockIdx.z;
    int w = threadIdx.x >> 6, lane = threadIdx.x & 63;
    int g = lane >> 3, dd = lane & 7;
    int bh = b*NH + hh;

    __shared__ float invs[KN*DH];
    {
        const float* invd = ws + DEN_OFF + (size_t)bh*KN*DH;
        for (int t = threadIdx.x; t < KN*DH; t += 256) invs[t] = invd[t];
    }
    __syncthreads();

    const float* Vbuf = ws + V_OFF + (size_t)bh*NN*DH;
    float* agg = ws + AGG_OFF + (size_t)bh*NN*DH;

    int i0 = blockIdx.x*8 + w*2;
    const unsigned short* num0 = (const unsigned short*)(ws + NUM_OFF)
                                 + ((size_t)bh*NN + i0)*KN*DH + dd;
    const unsigned short* num1 = num0 + (size_t)KN*DH;
    const int* ix0 = idx + (size_t)i0*KN;
    const int* ix1 = ix0 + KN;

    int p0 = ix0[g], p1 = ix1[g];
    float m0 = bfbits2f(num0[g*DH]), m1 = bfbits2f(num1[g*DH]);
    float acc0 = 0.f, acc1 = 0.f;

    for (int sg=0; sg<40; sg++){
        int jc = sg*8 + g;
        int jcc = jc < KN ? jc : (KN-1);
        float v0 = Vbuf[(size_t)p0*DH + dd];
        float v1 = Vbuf[(size_t)p1*DH + dd];
        float iv = invs[jcc*DH + dd];
        float w0 = m0 * iv, w1 = m1 * iv;
        if (jc >= KN){ w0 = 0.f; w1 = 0.f; }
        if (sg < 39){
            int jn = jc + 8; int jjn = jn < KN ? jn : (KN-1);
            p0 = ix0[jjn]; p1 = ix1[jjn];
            m0 = bfbits2f(num0[(size_t)jjn*DH]);
            m1 = bfbits2f(num1[(size_t)jjn*DH]);
        }
        acc0 = fmaf(w0, v0, acc0);
        acc1 = fmaf(w1, v1, acc1);
    }
    acc0 += __shfl_xor(acc0, 8, 64);
    acc0 += __shfl_xor(acc0, 16, 64);
    acc0 += __shfl_xor(acc0, 32, 64);
    acc1 += __shfl_xor(acc1, 8, 64);
    acc1 += __shfl_xor(acc1, 16, 64);
    acc1 += __shfl_xor(acc1, 32, 64);
    if (g == 0){
        agg[(size_t)i0*DH + dd]     = acc0;
        agg[(size_t)(i0+1)*DH + dd] = acc1;
    }
}

// ================= fallback path (small ws): round-3 proven kernels =================
__device__ __forceinline__ void load_w2p(const float* __restrict__ w2, int hh, int dd,
                                         v2f w2a[8], v2f w2b[8]){
    #pragma unroll
    for (int m=0; m<8; m++){
        int d = dd ^ (((m&1)<<2) | (m&2) | ((m>>2)&1));
        const float* wp = w2 + (hh*DH + d)*HID + 4*dd;
        v2f a; a.x = wp[0]; a.y = wp[1];
        v2f b; b.x = wp[2]; b.y = wp[3];
        w2a[m] = a; w2b[m] = b;
    }
}
__device__ __forceinline__ float butterfly8p(float pr[8]){
    float q0 = pr[0] + SWZ(pr[4], 0x041F);
    float q1 = pr[1] + SWZ(pr[5], 0x041F);
    float q2 = pr[2] + SWZ(pr[6], 0x041F);
    float q3 = pr[3] + SWZ(pr[7], 0x041F);
    float r0 = q0 + SWZ(q2, 0x081F);
    float r1 = q1 + SWZ(q3, 0x081F);
    return r0 + SWZ(r1, 0x101F);
}
__global__ __launch_bounds__(256, 4) void pass1_small(const int* __restrict__ idx,
                                                      const float* __restrict__ w2,
                                                      const float* __restrict__ b2, float* ws){
    int sgic = blockIdx.x, hh = blockIdx.y, b = blockIdx.z;
    int sg = sgic >> 4, ic = sgic & 15;
    int w = threadIdx.x >> 6, lane = threadIdx.x & 63;
    int g = lane >> 3, dd = lane & 7;
    int j = sg*8 + g;
    bool jv = (j < KN);
    int jj = jv ? j : (KN-1);
    int bh = b*NH + hh;

    v2f w2a[8], w2b[8];
    load_w2p(w2, hh, dd, w2a, w2b);
    float b2v = b2[hh*DH + dd];

    const float* Abuf = ws + A_OFF  + (size_t)bh*NN*HID + 4*dd;
    const float* Bbuf = ws + BK_OFF + (size_t)bh*NN*HID + 4*dd;
    const int* idxc = idx + jj;

    float den_acc = 0.f;
    int i0 = ic*144 + w*36;
    for (int ii=0; ii<36; ii++){
        int i = i0 + ii;
        int p = idxc[(size_t)i*KN];
        float4 avv = *(const float4*)(Abuf + (size_t)i*HID);
        float4 bvv = *(const float4*)(Bbuf + (size_t)p*HID);
        v2f a0; a0.x=avv.x; a0.y=avv.y;
        v2f a1; a1.x=avv.z; a1.y=avv.w;
        v2f c0; c0.x=bvv.x; c0.y=bvv.y;
        v2f c1; c1.x=bvv.z; c1.y=bvv.w;
        v2f z;  z.x=0.f; z.y=0.f;
        v2f r0 = __builtin_elementwise_max(a0-c0, z);
        v2f r1 = __builtin_elementwise_max(a1-c1, z);
        float pr[8];
        #pragma unroll
        for (int m=0; m<8; m++){
            v2f t = w2a[m]*r0;
            t = __builtin_elementwise_fma(w2b[m], r1, t);
            pr[m] = t.x + t.y;
        }
        float sim = butterfly8p(pr) + b2v;
        den_acc += __expf(sim);
    }
    if (!jv) den_acc = 0.f;

    __shared__ float red[256];
    red[threadIdx.x] = den_acc;
    __syncthreads();
    if (w == 0 && jv){
        float s = red[lane] + red[lane+64] + red[lane+128] + red[lane+192];
        atomicAdd(ws + DEN_OFF + ((size_t)bh*KN + j)*DH + dd, s);
    }
}
__device__ __forceinline__ void load_w2s(const float* __restrict__ w2, int hh, int dd, float w2s[8][4]){
    #pragma unroll
    for (int m=0; m<8; m++){
        int d = ((m&1)<<2) | (m&2) | ((m>>2)&1);
        const float* wp = w2 + (hh*DH + d)*HID + 4*dd;
        w2s[m][0]=wp[0]; w2s[m][1]=wp[1]; w2s[m][2]=wp[2]; w2s[m][3]=wp[3];
    }
}
__device__ __forceinline__ float butterfly8(float pr[8], int dd){
    int b0 = dd&1, b1 = (dd>>1)&1, b2b = (dd>>2)&1;
    float q[4];
    #pragma unroll
    for (int t=0; t<4; t++){
        float send = pr[4*(1-b0)+t];
        float recv = __shfl_xor(send, 1, 64);
        q[t] = pr[4*b0+t] + recv;
    }
    float r[2];
    #pragma unroll
    for (int t=0; t<2; t++){
        float send = q[2*(1-b1)+t];
        float recv = __shfl_xor(send, 2, 64);
        r[t] = q[2*b1+t] + recv;
    }
    float send = r[1-b2b];
    float recv = __shfl_xor(send, 4, 64);
    return r[b2b] + recv;
}
__global__ __launch_bounds__(256) void pass2_kernel(const int* __restrict__ idx,
                                                    const float* __restrict__ w2,
                                                    const float* __restrict__ b2, float* ws){
    int ic = blockIdx.x, hh = blockIdx.y, b = blockIdx.z;
    int w = threadIdx.x >> 6, lane = threadIdx.x & 63;
    int g = lane >> 3, dd = lane & 7;

    float w2s[8][4];
    load_w2s(w2, hh, dd, w2s);
    float b2v = b2[hh*DH + dd];

    const float* Abuf = ws + A_OFF  + (size_t)(b*NH + hh)*NN*HID;
    const float* Bbuf = ws + BK_OFF + (size_t)(b*NH + hh)*NN*HID;
    const float* Vbuf = ws + V_OFF  + (size_t)(b*NH + hh)*NN*DH;
    const float* invd = ws + DEN_OFF + (size_t)(b*NH + hh)*KN*DH;
    float*       agg  = ws + AGG_OFF + (size_t)(b*NH + hh)*NN*DH;

    int i0 = ic*8 + w*2;
    #pragma unroll
    for (int ii=0; ii<2; ii++){
        int i = i0 + ii;
        float4 av = *(const float4*)(Abuf + (size_t)i*HID + 4*dd);
        float acc = 0.f;
        for (int sg=0; sg<40; sg++){
            int j = sg*8 + g;
            bool jvv = (j < KN);
            int jj = jvv ? j : (KN-1);
            int p = idx[i*KN + jj];
            float4 bv = *(const float4*)(Bbuf + (size_t)p*HID + 4*dd);
            float r0 = fmaxf(av.x-bv.x, 0.f), r1 = fmaxf(av.y-bv.y, 0.f);
            float r2 = fmaxf(av.z-bv.z, 0.f), r3 = fmaxf(av.w-bv.w, 0.f);
            float pr[8];
            #pragma unroll
            for (int m=0; m<8; m++)
                pr[m] = fmaf(w2s[m][0],r0, fmaf(w2s[m][1],r1, fmaf(w2s[m][2],r2, w2s[m][3]*r3)));
            float sim = butterfly8(pr, dd) + b2v;
            float attn = jvv ? (__expf(sim) * invd[(size_t)jj*DH + dd]) : 0.f;
            acc = fmaf(attn, Vbuf[(size_t)p*DH + dd], acc);
        }
        acc += __shfl_xor(acc, 8, 64);
        acc += __shfl_xor(acc, 16, 64);
        acc += __shfl_xor(acc, 32, 64);
        if (g == 0) agg[(size_t)i*DH + dd] = acc;
    }
}

// ---------------- K5: out = agg @ w_out + b_out ----------------
__global__ void out_kernel(const float* __restrict__ w_out, const float* __restrict__ b_out,
                           const float* __restrict__ ws, float* __restrict__ out){
    int t = blockIdx.x*256 + threadIdx.x;
    if (t >= BB*NN*DIM) return;
    int c = t % DIM;
    int p = (t / DIM) % NN;
    int b = t / (DIM*NN);
    const float* agg = ws + AGG_OFF;
    float s = b_out[c];
    #pragma unroll
    for (int f=0; f<32; f++){
        int hh = f >> 3, d = f & 7;
        s = fmaf(agg[(((size_t)(b*NH + hh)*NN) + p)*DH + d], w_out[f*DIM + c], s);
    }
    out[t] = s;
}

extern "C" void kernel_launch(void* const* d_in, const int* in_sizes, int n_in,
                              void* d_out, int out_size, void* d_ws, size_t ws_size,
                              hipStream_t stream){
    const float* x     = (const float*)d_in[0];
    const int*   idx   = (const int*)d_in[1];
    const float* w_qkv = (const float*)d_in[2];
    const float* w1    = (const float*)d_in[3];
    const float* b1    = (const float*)d_in[4];
    const float* w2    = (const float*)d_in[5];
    const float* b2    = (const float*)d_in[6];
    const float* w_out = (const float*)d_in[7];
    const float* b_out = (const float*)d_in[8];
    float* ws  = (float*)d_ws;
    float* out = (float*)d_out;

    bool big = (ws_size >= WS_NEED_BYTES);

    hipMemsetAsync(ws + DEN_OFF, 0, DEN_SZ*sizeof(float), stream);

    qkv_kernel<<<(BB*NN*96 + 255)/256, 256, 0, stream>>>(x, w_qkv, ws);
    ab_kernel <<<(BB*NH*NN*HID + 255)/256, 256, 0, stream>>>(w1, b1, ws);
    if (big){
        pass1_mfma<<<dim3(20, 8, BB*NH), 256, 0, stream>>>(idx, w2, b2, ws);
        invden_kernel<<<(DEN_SZ + 255)/256, 256, 0, stream>>>(ws);
        pass2f_kernel<<<dim3(288, NH, BB), 256, 0, stream>>>(idx, ws);
    } else {
        pass1_small<<<dim3(640, NH, BB), 256, 0, stream>>>(idx, w2, b2, ws);
        invden_kernel<<<(DEN_SZ + 255)/256, 256, 0, stream>>>(ws);
        pass2_kernel<<<dim3(288, NH, BB), 256, 0, stream>>>(idx, w2, b2, ws);
    }
    out_kernel<<<(BB*NN*DIM + 255)/256, 256, 0, stream>>>(w_out, b_out, ws, out);
}